// Round 9
// baseline (233.283 us; speedup 1.0000x reference)
//
#include <hip/hip_runtime.h>
#include <hip/hip_bf16.h>

// CrossAttention MI355X — Round 9.
//  - attn v6: q-tile 64, 256 thr, grid 1024 (4 blocks/CU); global_load_lds
//    staging; P passes C->A layout entirely in registers via shfl_xor(32)
//    half-swap (no Ps LDS buffer). 32x32x16 MFMA throughout.
//  - gemm_qk: 128x64 tiles, grid (16,32,2)=1024 (4 blocks/CU).
//  - gemm_proj: unchanged 64x64 grid 1024 + launch_bounds.
// Reference quirk: k = v = kv[:,:,0] -> only W_kv rows [0,1024) matter.

typedef __bf16 bf16x8 __attribute__((ext_vector_type(8)));
typedef float f32x4 __attribute__((ext_vector_type(4)));
typedef float f32x16 __attribute__((ext_vector_type(16)));

static constexpr int kDIM = 1024;
static constexpr float kLog2e = 1.4426950408889634f;

__device__ inline unsigned short f2bf(float f) {      // RNE
    union { float f; unsigned int u; } v; v.f = f;
    return (unsigned short)((v.u + 0x7FFFu + ((v.u >> 16) & 1u)) >> 16);
}

// round-half-up bf16 pair-pack: low16 = a, high16 = b
__device__ inline unsigned int pack2bf(float a, float b) {
    union { float f; unsigned int u; } ua, ub;
    ua.f = a; ub.f = b;
    return __builtin_amdgcn_perm(ub.u + 0x8000u, ua.u + 0x8000u, 0x07060302u);
}

// async global->LDS, 16 B per lane; LDS dest = wave-uniform base + lane*16
__device__ inline void gload_lds16(const unsigned short* g, unsigned short* l) {
    __builtin_amdgcn_global_load_lds(
        (const __attribute__((address_space(1))) unsigned int*)g,
        (__attribute__((address_space(3))) unsigned int*)l, 16, 0, 0);
}

// ---------------------------------------------------------------------------
// Single cast kernel (unchanged).
// ---------------------------------------------------------------------------
__global__ __launch_bounds__(256) void cast_all(
    const float* __restrict__ x, const float* __restrict__ ctx,
    const float* __restrict__ wq, const float* __restrict__ wkv,
    const float* __restrict__ wp,
    unsigned short* __restrict__ xb, unsigned short* __restrict__ cb,
    unsigned short* __restrict__ wqb, unsigned short* __restrict__ wkb,
    unsigned short* __restrict__ wpb)
{
    int j = blockIdx.x * 256 + threadIdx.x;   // float4 index
    const float* s; unsigned short* d;
    if (j < 1048576)                      { s = x;   d = xb;  }
    else if ((j -= 1048576) < 1048576)    { s = ctx; d = cb;  }
    else if ((j -= 1048576) < 262144)     { s = wq;  d = wqb; }
    else if ((j -= 262144) < 262144)      { s = wkv; d = wkb; }
    else if ((j -= 262144) < 262144)      { s = wp;  d = wpb; }
    else return;
    float4 f = ((const float4*)s)[j];
    ushort4 o;
    o.x = f2bf(f.x); o.y = f2bf(f.y); o.z = f2bf(f.z); o.w = f2bf(f.w);
    ((ushort4*)d)[j] = o;
}

// ---------------------------------------------------------------------------
// Fused Q/K projection GEMM: 128(m)x64(n) tile, 256 threads (4 waves, 2x2 of
// 64x32), BK=64, global_load_lds staging, grid (16,32,2) = 1024 blocks.
// z=0: Qb = qscale * x @ Wq^T ; z=1: Kb = ctx @ Wkv^T (+ K^T layout Ktb).
// ---------------------------------------------------------------------------
__global__ __launch_bounds__(256, 4) void gemm_qk(
    const unsigned short* __restrict__ xb, const unsigned short* __restrict__ cb,
    const unsigned short* __restrict__ Wq, const unsigned short* __restrict__ Wkv,
    unsigned short* __restrict__ Qb, unsigned short* __restrict__ Kb,
    unsigned short* __restrict__ Ktb, float qscale, int Mctx)
{
    __shared__ unsigned short As[128 * 64];
    __shared__ unsigned short Bs[64 * 64];
    const int z = blockIdx.z;
    const unsigned short* A  = z ? cb : xb;
    const unsigned short* Bw = z ? Wkv : Wq;
    unsigned short* Cb = z ? Kb : Qb;
    const float scale = z ? 1.0f : qscale;

    const int tid = threadIdx.x;
    const int wave = tid >> 6, lane = tid & 63;
    const int g = lane >> 4, c = lane & 15;
    const int wm = (wave & 1) * 64, wn = (wave >> 1) * 32;
    const int bm = blockIdx.y * 128, bn = blockIdx.x * 64;

    const int srow = lane >> 3, scol = (lane & 7) * 8;

    f32x4 acc[4][2];
    #pragma unroll
    for (int i = 0; i < 4; ++i)
        #pragma unroll
        for (int j = 0; j < 2; ++j)
            acc[i][j] = (f32x4){0.f, 0.f, 0.f, 0.f};

    for (int k0 = 0; k0 < kDIM; k0 += 64) {
        __syncthreads();
        #pragma unroll
        for (int t = 0; t < 4; ++t) {                 // A: 16 chunks
            const int chunk = wave * 4 + t;
            gload_lds16(A + (size_t)(bm + chunk * 8 + srow) * kDIM + k0 + scol,
                        &As[chunk * 512]);
        }
        #pragma unroll
        for (int t = 0; t < 2; ++t) {                 // B: 8 chunks
            const int chunk = wave * 2 + t;
            gload_lds16(Bw + (size_t)(bn + chunk * 8 + srow) * kDIM + k0 + scol,
                        &Bs[chunk * 512]);
        }
        __syncthreads();
        #pragma unroll
        for (int kc = 0; kc < 2; ++kc) {
            bf16x8 af[4], bfr[2];
            #pragma unroll
            for (int i = 0; i < 4; ++i)
                af[i] = *(const bf16x8*)&As[(wm + i * 16 + c) * 64 + kc * 32 + g * 8];
            #pragma unroll
            for (int j = 0; j < 2; ++j)
                bfr[j] = *(const bf16x8*)&Bs[(wn + j * 16 + c) * 64 + kc * 32 + g * 8];
            #pragma unroll
            for (int i = 0; i < 4; ++i)
                #pragma unroll
                for (int j = 0; j < 2; ++j)
                    acc[i][j] = __builtin_amdgcn_mfma_f32_16x16x32_bf16(
                        af[i], bfr[j], acc[i][j], 0, 0, 0);
        }
    }

    #pragma unroll
    for (int i = 0; i < 4; ++i) {
        #pragma unroll
        for (int j = 0; j < 2; ++j) {
            const int r0 = bm + wm + i * 16 + 4 * g;
            const int cc = bn + wn + j * 16 + c;
            float v0 = acc[i][j][0] * scale;
            float v1 = acc[i][j][1] * scale;
            float v2 = acc[i][j][2] * scale;
            float v3 = acc[i][j][3] * scale;
            Cb[(size_t)(r0 + 0) * kDIM + cc] = f2bf(v0);
            Cb[(size_t)(r0 + 1) * kDIM + cc] = f2bf(v1);
            Cb[(size_t)(r0 + 2) * kDIM + cc] = f2bf(v2);
            Cb[(size_t)(r0 + 3) * kDIM + cc] = f2bf(v3);
            if (z) {
                const int bb = r0 / Mctx, n0 = r0 % Mctx;
                const int hh = cc >> 6, d = cc & 63;
                ushort4 pk;
                pk.x = f2bf(v0); pk.y = f2bf(v1); pk.z = f2bf(v2); pk.w = f2bf(v3);
                *(ushort4*)&Ktb[((size_t)((bb * 16 + hh) * 64 + d)) * Mctx + n0] = pk;
            }
        }
    }
}

// ---------------------------------------------------------------------------
// Proj GEMM: 64x64 tiles, grid 1024 (4 blocks/CU), 256 threads, BK=64.
// ---------------------------------------------------------------------------
__global__ __launch_bounds__(256, 4) void gemm_proj(
    const unsigned short* __restrict__ Ab, const unsigned short* __restrict__ Wp,
    const float* __restrict__ bias, float* __restrict__ out)
{
    __shared__ unsigned short As[64 * 64];
    __shared__ unsigned short Bs[64 * 64];
    const int tid = threadIdx.x;
    const int wave = tid >> 6, lane = tid & 63;
    const int g = lane >> 4, c = lane & 15;
    const int wm = (wave & 1) * 32, wn = (wave >> 1) * 32;
    const int bm = blockIdx.y * 64, bn = blockIdx.x * 64;

    const int srow = lane >> 3, scol = (lane & 7) * 8;

    f32x4 acc[2][2];
    #pragma unroll
    for (int i = 0; i < 2; ++i)
        #pragma unroll
        for (int j = 0; j < 2; ++j)
            acc[i][j] = (f32x4){0.f, 0.f, 0.f, 0.f};

    for (int k0 = 0; k0 < kDIM; k0 += 64) {
        __syncthreads();
        #pragma unroll
        for (int t = 0; t < 2; ++t) {
            const int chunk = wave * 2 + t;              // 0..7
            const int row = chunk * 8 + srow;
            gload_lds16(Ab + (size_t)(bm + row) * kDIM + k0 + scol, &As[chunk * 512]);
            gload_lds16(Wp + (size_t)(bn + row) * kDIM + k0 + scol, &Bs[chunk * 512]);
        }
        __syncthreads();
        #pragma unroll
        for (int kc = 0; kc < 2; ++kc) {
            bf16x8 af[2], bfr[2];
            #pragma unroll
            for (int i = 0; i < 2; ++i)
                af[i] = *(const bf16x8*)&As[(wm + i * 16 + c) * 64 + kc * 32 + g * 8];
            #pragma unroll
            for (int j = 0; j < 2; ++j)
                bfr[j] = *(const bf16x8*)&Bs[(wn + j * 16 + c) * 64 + kc * 32 + g * 8];
            #pragma unroll
            for (int i = 0; i < 2; ++i)
                #pragma unroll
                for (int j = 0; j < 2; ++j)
                    acc[i][j] = __builtin_amdgcn_mfma_f32_16x16x32_bf16(
                        af[i], bfr[j], acc[i][j], 0, 0, 0);
        }
    }

    #pragma unroll
    for (int i = 0; i < 2; ++i) {
        #pragma unroll
        for (int j = 0; j < 2; ++j) {
            const int r0 = bm + wm + i * 16 + 4 * g;
            const int cc = bn + wn + j * 16 + c;
            const float bv = bias[cc];
            #pragma unroll
            for (int ii = 0; ii < 4; ++ii)
                out[(size_t)(r0 + ii) * kDIM + cc] = acc[i][j][ii] + bv;
        }
    }
}

// ---------------------------------------------------------------------------
// Flash attention v6: 256 threads = 4 waves = 2 q-strips x 2 key-halves.
// q-tile 64, grid (N/64, 16, B) = 1024 blocks (4/CU). 32x32x16 MFMA.
// S^T C-layout -> PV B-layout conversion fully in registers via
// shfl_xor(32) half-swap. Staging via global_load_lds DMA. Key-half
// partials merged once via LDS at the end.
// ---------------------------------------------------------------------------
__global__ __launch_bounds__(256, 4) void attn_mfma_v6(
    const unsigned short* __restrict__ Q,   // [B*N][1024]
    const unsigned short* __restrict__ K,   // [B*M][1024]
    const unsigned short* __restrict__ Kt,  // [(B*16+h)*64+d][M]
    unsigned short* __restrict__ O, int N, int M)
{
    __shared__ float smemf[64 * 68 + 64];          // 17,664 B (merge view)
    unsigned short* Ks  = (unsigned short*)smemf;  // [64][64] keys x d
    unsigned short* Kts = Ks + 64 * 64;            // [64][64] d x keys
    float* Om = smemf;                             // [64][68]
    float* Lm = smemf + 64 * 68;                   // [64]

    const int b = blockIdx.z, h = blockIdx.y, q0 = blockIdx.x * 64;
    const int tid = threadIdx.x;
    const int w = tid >> 6, lane = tid & 63;
    const int strip = w >> 1, kh = w & 1;
    const int ql = lane & 31, l5 = lane >> 5;
    const int srow = lane >> 3, scol = (lane & 7) * 8;

    const unsigned short* Qrow = Q + (size_t)(b * N + q0 + strip * 32 + ql) * kDIM + h * 64;
    const unsigned short* Kb = K + (size_t)b * M * kDIM + h * 64;
    const unsigned short* Ktb = Kt + (size_t)((b * 16 + h) * 64) * M;

    // Hoisted Q B-frags: B[n=q][k=d], d-chunks of 16.
    bf16x8 bq[4];
    #pragma unroll
    for (int kc = 0; kc < 4; ++kc)
        bq[kc] = *(const bf16x8*)(Qrow + kc * 16 + l5 * 8);

    f32x16 ot[2];
    #pragma unroll
    for (int dt = 0; dt < 2; ++dt)
        #pragma unroll
        for (int r = 0; r < 16; ++r) ot[dt][r] = 0.f;
    float lac = 0.f;

    for (int k0 = 0; k0 < M; k0 += 64) {
        __syncthreads();
        #pragma unroll
        for (int t = 0; t < 2; ++t) {                 // 8+8 chunks / 4 waves
            const int chunk = w * 2 + t;
            gload_lds16(Kb + (size_t)(k0 + chunk * 8 + srow) * kDIM + scol,
                        &Ks[chunk * 512]);
            gload_lds16(Ktb + (size_t)(chunk * 8 + srow) * M + k0 + scol,
                        &Kts[chunk * 512]);
        }
        __syncthreads();

        // S^T (this wave's 32-key half x 32 q): A = K, B = Q.
        f32x16 st;
        #pragma unroll
        for (int r = 0; r < 16; ++r) st[r] = 0.f;
        #pragma unroll
        for (int kc = 0; kc < 4; ++kc) {
            bf16x8 ak = *(const bf16x8*)&Ks[(kh * 32 + ql) * 64 + kc * 16 + l5 * 8];
            st = __builtin_amdgcn_mfma_f32_32x32x16_bf16(ak, bq[kc], st, 0, 0, 0);
        }

        // p = 2^s (lane: q=ql fixed, key=(r&3)+8*(r>>2)+4*l5), row-sum partials.
        float pr[16];
        #pragma unroll
        for (int r = 0; r < 16; ++r) {
            pr[r] = __builtin_amdgcn_exp2f(st[r]);
            lac += pr[r];
        }
        // Pack key-pairs and half-swap with lane^32 to build PV B-frags
        // (B[n=q][k=key]: lane needs keys kc2*16 + l5*8 .. +7).
        unsigned int dw[8], ex[8];
        #pragma unroll
        for (int p = 0; p < 8; ++p) dw[p] = pack2bf(pr[2 * p], pr[2 * p + 1]);
        #pragma unroll
        for (int p = 0; p < 8; ++p) ex[p] = (unsigned int)__shfl_xor((int)dw[p], 32);
        union FU { unsigned int u[4]; bf16x8 v; } bp0, bp1;
        const bool hi = (l5 != 0);
        bp0.u[0] = hi ? ex[2] : dw[0];
        bp0.u[1] = hi ? ex[3] : dw[1];
        bp0.u[2] = hi ? dw[2] : ex[0];
        bp0.u[3] = hi ? dw[3] : ex[1];
        bp1.u[0] = hi ? ex[6] : dw[4];
        bp1.u[1] = hi ? ex[7] : dw[5];
        bp1.u[2] = hi ? dw[6] : ex[4];
        bp1.u[3] = hi ? dw[7] : ex[5];

        // O^T += V^T . P  (A = V^T from Kts, B = P in registers).
        #pragma unroll
        for (int kc2 = 0; kc2 < 2; ++kc2) {
            const bf16x8 bp = kc2 ? bp1.v : bp0.v;
            #pragma unroll
            for (int dt = 0; dt < 2; ++dt) {
                bf16x8 av = *(const bf16x8*)&Kts[(dt * 32 + ql) * 64 + kh * 32 + kc2 * 16 + l5 * 8];
                ot[dt] = __builtin_amdgcn_mfma_f32_32x32x16_bf16(av, bp, ot[dt], 0, 0, 0);
            }
        }
    }

    // Merge the two key-halves via LDS, normalize, store.
    float lw = lac + __shfl_xor(lac, 32);       // full sum over this half
    const int qi = strip * 32 + ql;

    __syncthreads();                            // staging reads done; reuse LDS
    if (kh == 1) {
        #pragma unroll
        for (int dt = 0; dt < 2; ++dt)
            #pragma unroll
            for (int rr = 0; rr < 4; ++rr)
                *(f32x4*)&Om[qi * 68 + dt * 32 + 8 * rr + 4 * l5] =
                    (f32x4){ot[dt][4 * rr], ot[dt][4 * rr + 1],
                            ot[dt][4 * rr + 2], ot[dt][4 * rr + 3]};
        if (l5 == 0) Lm[qi] = lw;
    }
    __syncthreads();
    if (kh == 0) {
        const float inv = 1.0f / (lw + Lm[qi]);
        unsigned short* Ob = O + (size_t)(b * N + q0 + qi) * kDIM + h * 64;
        #pragma unroll
        for (int dt = 0; dt < 2; ++dt)
            #pragma unroll
            for (int rr = 0; rr < 4; ++rr) {
                f32x4 pv = *(const f32x4*)&Om[qi * 68 + dt * 32 + 8 * rr + 4 * l5];
                ushort4 u;
                u.x = f2bf((ot[dt][4 * rr]     + pv[0]) * inv);
                u.y = f2bf((ot[dt][4 * rr + 1] + pv[1]) * inv);
                u.z = f2bf((ot[dt][4 * rr + 2] + pv[2]) * inv);
                u.w = f2bf((ot[dt][4 * rr + 3] + pv[3]) * inv);
                *(ushort4*)(Ob + dt * 32 + 8 * rr + 4 * l5) = u;
            }
    }
}

// ---------------------------------------------------------------------------
extern "C" void kernel_launch(void* const* d_in, const int* in_sizes, int n_in,
                              void* d_out, int out_size, void* d_ws, size_t ws_size,
                              hipStream_t stream)
{
    const float* x      = (const float*)d_in[0];
    const float* ctxp   = (const float*)d_in[1];
    const float* W_q    = (const float*)d_in[2];
    const float* W_kv   = (const float*)d_in[3];
    const float* W_proj = (const float*)d_in[4];
    const float* b_proj = (const float*)d_in[5];
    float* out = (float*)d_out;

    const int B = 2, N = 2048, M = 2048;
    const int BN = B * N;        // 4096
    const int SQ = kDIM * kDIM;  // 1M

    unsigned short* p = (unsigned short*)d_ws;
    unsigned short* xb  = p; p += (size_t)BN * kDIM;   // reused as Ab
    unsigned short* cb  = p; p += (size_t)BN * kDIM;
    unsigned short* wqb = p; p += SQ;
    unsigned short* wkb = p; p += SQ;
    unsigned short* wpb = p; p += SQ;
    unsigned short* Qb  = p; p += (size_t)BN * kDIM;
    unsigned short* Kb  = p; p += (size_t)BN * kDIM;
    unsigned short* Ktb = p; p += (size_t)BN * kDIM;
    unsigned short* Ab  = xb;    // xb dead after gemm_qk

    // 1) fp32 -> bf16 for all inputs
    hipLaunchKernelGGL(cast_all, dim3(11264), dim3(256), 0, stream,
                       x, ctxp, W_q, W_kv, W_proj, xb, cb, wqb, wkb, wpb);
    // 2) z=0: Q = (0.125*log2e) * x @ Wq^T ; z=1: K(=V) = ctx @ Wkv^T (+ K^T)
    hipLaunchKernelGGL(gemm_qk, dim3(kDIM / 64, BN / 128, 2), dim3(256), 0, stream,
                       xb, cb, wqb, wkb, Qb, Kb, Ktb, 0.125f * kLog2e, M);
    // 3) A = softmax(Q K^T) V
    hipLaunchKernelGGL(attn_mfma_v6, dim3(N / 64, 16, B), dim3(256), 0, stream,
                       Qb, Kb, Ktb, Ab, N, M);
    // 4) out = A @ Wp^T + bias
    hipLaunchKernelGGL(gemm_proj, dim3(kDIM / 64, BN / 64), dim3(256), 0, stream,
                       Ab, wpb, b_proj, out);
}

// Round 10
// 190.938 us; speedup vs baseline: 1.2218x; 1.2218x over previous
//
#include <hip/hip_runtime.h>
#include <hip/hip_bf16.h>

// CrossAttention MI355X — Round 10.
//  - attn v5 reverted to R8 exactly (57.4 us; R9's unpadded-LDS variant put
//    all 64 lanes in 2/8 bank groups -> 4x b128 floor, 97 us).
//  - GEMMs: XOR-swizzled global_load_lds staging (phys cg = logical cg ^
//    (row&7)) -> frag b128 reads hit all 32 banks (BW floor) instead of half.
// Reference quirk: k = v = kv[:,:,0] -> only W_kv rows [0,1024) matter.

typedef __bf16 bf16x8 __attribute__((ext_vector_type(8)));
typedef float f32x4 __attribute__((ext_vector_type(4)));
typedef float f32x16 __attribute__((ext_vector_type(16)));

static constexpr int kDIM = 1024;
static constexpr float kLog2e = 1.4426950408889634f;

__device__ inline unsigned short f2bf(float f) {      // RNE
    union { float f; unsigned int u; } v; v.f = f;
    return (unsigned short)((v.u + 0x7FFFu + ((v.u >> 16) & 1u)) >> 16);
}

// round-half-up bf16 pair-pack: low16 = a, high16 = b
__device__ inline unsigned int pack2bf(float a, float b) {
    union { float f; unsigned int u; } ua, ub;
    ua.f = a; ub.f = b;
    return __builtin_amdgcn_perm(ub.u + 0x8000u, ua.u + 0x8000u, 0x07060302u);
}

// async global->LDS, 16 B per lane; LDS dest = wave-uniform base + lane*16
__device__ inline void gload_lds16(const unsigned short* g, unsigned short* l) {
    __builtin_amdgcn_global_load_lds(
        (const __attribute__((address_space(1))) unsigned int*)g,
        (__attribute__((address_space(3))) unsigned int*)l, 16, 0, 0);
}

// ---------------------------------------------------------------------------
// Single cast kernel (unchanged).
// ---------------------------------------------------------------------------
__global__ __launch_bounds__(256) void cast_all(
    const float* __restrict__ x, const float* __restrict__ ctx,
    const float* __restrict__ wq, const float* __restrict__ wkv,
    const float* __restrict__ wp,
    unsigned short* __restrict__ xb, unsigned short* __restrict__ cb,
    unsigned short* __restrict__ wqb, unsigned short* __restrict__ wkb,
    unsigned short* __restrict__ wpb)
{
    int j = blockIdx.x * 256 + threadIdx.x;   // float4 index
    const float* s; unsigned short* d;
    if (j < 1048576)                      { s = x;   d = xb;  }
    else if ((j -= 1048576) < 1048576)    { s = ctx; d = cb;  }
    else if ((j -= 1048576) < 262144)     { s = wq;  d = wqb; }
    else if ((j -= 262144) < 262144)      { s = wkv; d = wkb; }
    else if ((j -= 262144) < 262144)      { s = wp;  d = wpb; }
    else return;
    float4 f = ((const float4*)s)[j];
    ushort4 o;
    o.x = f2bf(f.x); o.y = f2bf(f.y); o.z = f2bf(f.z); o.w = f2bf(f.w);
    ((ushort4*)d)[j] = o;
}

// ---------------------------------------------------------------------------
// Fused Q/K projection GEMM: 128(m)x64(n) tile, 256 thr (2x2 waves of 64x32),
// BK=64, XOR-swizzled global_load_lds staging, grid (16,32,2) = 1024 blocks.
// z=0: Qb = qscale * x @ Wq^T ; z=1: Kb = ctx @ Wkv^T (+ K^T layout Ktb).
// LDS layout: elem(row, physcg*8..+7), physcg = logicalcg ^ (row&7).
// ---------------------------------------------------------------------------
__global__ __launch_bounds__(256, 4) void gemm_qk(
    const unsigned short* __restrict__ xb, const unsigned short* __restrict__ cb,
    const unsigned short* __restrict__ Wq, const unsigned short* __restrict__ Wkv,
    unsigned short* __restrict__ Qb, unsigned short* __restrict__ Kb,
    unsigned short* __restrict__ Ktb, float qscale, int Mctx)
{
    __shared__ unsigned short As[128 * 64];
    __shared__ unsigned short Bs[64 * 64];
    const int z = blockIdx.z;
    const unsigned short* A  = z ? cb : xb;
    const unsigned short* Bw = z ? Wkv : Wq;
    unsigned short* Cb = z ? Kb : Qb;
    const float scale = z ? 1.0f : qscale;

    const int tid = threadIdx.x;
    const int wave = tid >> 6, lane = tid & 63;
    const int g = lane >> 4, c = lane & 15;
    const int wm = (wave & 1) * 64, wn = (wave >> 1) * 32;
    const int bm = blockIdx.y * 128, bn = blockIdx.x * 64;

    const int srow = lane >> 3;
    const int scolsw = ((lane & 7) ^ (srow & 7)) * 8;   // swizzled source col
    const int x7 = c & 7;                               // frag-read XOR term

    f32x4 acc[4][2];
    #pragma unroll
    for (int i = 0; i < 4; ++i)
        #pragma unroll
        for (int j = 0; j < 2; ++j)
            acc[i][j] = (f32x4){0.f, 0.f, 0.f, 0.f};

    for (int k0 = 0; k0 < kDIM; k0 += 64) {
        __syncthreads();
        #pragma unroll
        for (int t = 0; t < 4; ++t) {                 // A: 16 chunks
            const int chunk = wave * 4 + t;
            gload_lds16(A + (size_t)(bm + chunk * 8 + srow) * kDIM + k0 + scolsw,
                        &As[chunk * 512]);
        }
        #pragma unroll
        for (int t = 0; t < 2; ++t) {                 // B: 8 chunks
            const int chunk = wave * 2 + t;
            gload_lds16(Bw + (size_t)(bn + chunk * 8 + srow) * kDIM + k0 + scolsw,
                        &Bs[chunk * 512]);
        }
        __syncthreads();
        #pragma unroll
        for (int kc = 0; kc < 2; ++kc) {
            bf16x8 af[4], bfr[2];
            #pragma unroll
            for (int i = 0; i < 4; ++i)
                af[i] = *(const bf16x8*)&As[(wm + i * 16 + c) * 64 +
                                            ((kc * 4 + g) ^ x7) * 8];
            #pragma unroll
            for (int j = 0; j < 2; ++j)
                bfr[j] = *(const bf16x8*)&Bs[(wn + j * 16 + c) * 64 +
                                             ((kc * 4 + g) ^ x7) * 8];
            #pragma unroll
            for (int i = 0; i < 4; ++i)
                #pragma unroll
                for (int j = 0; j < 2; ++j)
                    acc[i][j] = __builtin_amdgcn_mfma_f32_16x16x32_bf16(
                        af[i], bfr[j], acc[i][j], 0, 0, 0);
        }
    }

    #pragma unroll
    for (int i = 0; i < 4; ++i) {
        #pragma unroll
        for (int j = 0; j < 2; ++j) {
            const int r0 = bm + wm + i * 16 + 4 * g;
            const int cc = bn + wn + j * 16 + c;
            float v0 = acc[i][j][0] * scale;
            float v1 = acc[i][j][1] * scale;
            float v2 = acc[i][j][2] * scale;
            float v3 = acc[i][j][3] * scale;
            Cb[(size_t)(r0 + 0) * kDIM + cc] = f2bf(v0);
            Cb[(size_t)(r0 + 1) * kDIM + cc] = f2bf(v1);
            Cb[(size_t)(r0 + 2) * kDIM + cc] = f2bf(v2);
            Cb[(size_t)(r0 + 3) * kDIM + cc] = f2bf(v3);
            if (z) {
                const int bb = r0 / Mctx, n0 = r0 % Mctx;
                const int hh = cc >> 6, d = cc & 63;
                ushort4 pk;
                pk.x = f2bf(v0); pk.y = f2bf(v1); pk.z = f2bf(v2); pk.w = f2bf(v3);
                *(ushort4*)&Ktb[((size_t)((bb * 16 + hh) * 64 + d)) * Mctx + n0] = pk;
            }
        }
    }
}

// ---------------------------------------------------------------------------
// Proj GEMM: 64x64 tiles, grid (16,64) = 1024 blocks, 256 thr, BK=64,
// XOR-swizzled DMA staging.
// ---------------------------------------------------------------------------
__global__ __launch_bounds__(256, 4) void gemm_proj(
    const unsigned short* __restrict__ Ab, const unsigned short* __restrict__ Wp,
    const float* __restrict__ bias, float* __restrict__ out)
{
    __shared__ unsigned short As[64 * 64];
    __shared__ unsigned short Bs[64 * 64];
    const int tid = threadIdx.x;
    const int wave = tid >> 6, lane = tid & 63;
    const int g = lane >> 4, c = lane & 15;
    const int wm = (wave & 1) * 32, wn = (wave >> 1) * 32;
    const int bm = blockIdx.y * 64, bn = blockIdx.x * 64;

    const int srow = lane >> 3;
    const int scolsw = ((lane & 7) ^ (srow & 7)) * 8;
    const int x7 = c & 7;

    f32x4 acc[2][2];
    #pragma unroll
    for (int i = 0; i < 2; ++i)
        #pragma unroll
        for (int j = 0; j < 2; ++j)
            acc[i][j] = (f32x4){0.f, 0.f, 0.f, 0.f};

    for (int k0 = 0; k0 < kDIM; k0 += 64) {
        __syncthreads();
        #pragma unroll
        for (int t = 0; t < 2; ++t) {
            const int chunk = wave * 2 + t;              // 0..7
            const int row = chunk * 8 + srow;
            gload_lds16(Ab + (size_t)(bm + row) * kDIM + k0 + scolsw, &As[chunk * 512]);
            gload_lds16(Wp + (size_t)(bn + row) * kDIM + k0 + scolsw, &Bs[chunk * 512]);
        }
        __syncthreads();
        #pragma unroll
        for (int kc = 0; kc < 2; ++kc) {
            bf16x8 af[2], bfr[2];
            #pragma unroll
            for (int i = 0; i < 2; ++i)
                af[i] = *(const bf16x8*)&As[(wm + i * 16 + c) * 64 +
                                            ((kc * 4 + g) ^ x7) * 8];
            #pragma unroll
            for (int j = 0; j < 2; ++j)
                bfr[j] = *(const bf16x8*)&Bs[(wn + j * 16 + c) * 64 +
                                             ((kc * 4 + g) ^ x7) * 8];
            #pragma unroll
            for (int i = 0; i < 2; ++i)
                #pragma unroll
                for (int j = 0; j < 2; ++j)
                    acc[i][j] = __builtin_amdgcn_mfma_f32_16x16x32_bf16(
                        af[i], bfr[j], acc[i][j], 0, 0, 0);
        }
    }

    #pragma unroll
    for (int i = 0; i < 2; ++i) {
        #pragma unroll
        for (int j = 0; j < 2; ++j) {
            const int r0 = bm + wm + i * 16 + 4 * g;
            const int cc = bn + wn + j * 16 + c;
            const float bv = bias[cc];
            #pragma unroll
            for (int ii = 0; ii < 4; ++ii)
                out[(size_t)(r0 + ii) * kDIM + cc] = acc[i][j][ii] + bv;
        }
    }
}

// ---------------------------------------------------------------------------
// Flash attention v5 (R8 verbatim): 512 threads = 8 waves = 4 q-strips x 2
// key-halves. 32x32x16 MFMA, S^T layout, P via padded-72 LDS (bank-rotating),
// key-half partials merged once via LDS at the end.
// ---------------------------------------------------------------------------
__global__ __launch_bounds__(512, 4) void attn_mfma_v5(
    const unsigned short* __restrict__ Q,   // [B*N][1024]
    const unsigned short* __restrict__ K,   // [B*M][1024]
    const unsigned short* __restrict__ Kt,  // [(B*16+h)*64+d][M]
    unsigned short* __restrict__ O, int N, int M)
{
    __shared__ unsigned short smem[18432];        // 36,864 B
    unsigned short* Ks  = smem;                   // [64][72]
    unsigned short* Kts = smem + 64 * 72;         // [64][72]
    unsigned short* Ps  = smem + 2 * 64 * 72;     // [128][72]

    const int b = blockIdx.z, h = blockIdx.y, q0 = blockIdx.x * 128;
    const int tid = threadIdx.x;
    const int w = tid >> 6, lane = tid & 63;
    const int strip = w >> 1, kh = w & 1;
    const int ql = lane & 31, l5 = lane >> 5;

    const unsigned short* Qrow = Q + (size_t)(b * N + q0 + strip * 32 + ql) * kDIM + h * 64;
    const unsigned short* Kb = K + (size_t)b * M * kDIM + h * 64;
    const unsigned short* Ktb = Kt + (size_t)((b * 16 + h) * 64) * M;

    bf16x8 bq[4];
    #pragma unroll
    for (int kc = 0; kc < 4; ++kc)
        bq[kc] = *(const bf16x8*)(Qrow + kc * 16 + l5 * 8);

    f32x16 ot[2];
    #pragma unroll
    for (int dt = 0; dt < 2; ++dt)
        #pragma unroll
        for (int r = 0; r < 16; ++r) ot[dt][r] = 0.f;
    float lac = 0.f;

    const int srow = tid >> 3, scol = (tid & 7) * 8;
    unsigned short* prow = &Ps[(strip * 32 + ql) * 72 + kh * 32];

    for (int k0 = 0; k0 < M; k0 += 64) {
        __syncthreads();
        *(uint4*)&Ks[srow * 72 + scol] =
            *(const uint4*)(Kb + (size_t)(k0 + srow) * kDIM + scol);
        *(uint4*)&Kts[srow * 72 + scol] =
            *(const uint4*)(Ktb + (size_t)srow * M + k0 + scol);
        __syncthreads();

        // S^T (32 keys of this wave's half x 32 q): A = K, B = Q.
        f32x16 st;
        #pragma unroll
        for (int r = 0; r < 16; ++r) st[r] = 0.f;
        #pragma unroll
        for (int kc = 0; kc < 4; ++kc) {
            bf16x8 ak = *(const bf16x8*)&Ks[(kh * 32 + ql) * 72 + kc * 16 + l5 * 8];
            st = __builtin_amdgcn_mfma_f32_32x32x16_bf16(ak, bq[kc], st, 0, 0, 0);
        }

        // p = 2^s; per-lane partial row sums; pack key-pairs; b64 Ps writes.
        float pr[16];
        #pragma unroll
        for (int r = 0; r < 16; ++r) {
            pr[r] = __builtin_amdgcn_exp2f(st[r]);
            lac += pr[r];
        }
        unsigned int dw[8];
        #pragma unroll
        for (int p = 0; p < 8; ++p) dw[p] = pack2bf(pr[2 * p], pr[2 * p + 1]);
        #pragma unroll
        for (int pp = 0; pp < 4; ++pp)
            *(uint2*)&prow[8 * pp + 4 * l5] = make_uint2(dw[2 * pp], dw[2 * pp + 1]);
        // wave-private Ps rows/cols: no barrier needed

        // O^T += V^T . P  (A = V^T from Kts, B = P from Ps)
        #pragma unroll
        for (int kc2 = 0; kc2 < 2; ++kc2) {
            bf16x8 bp = *(const bf16x8*)&prow[kc2 * 16 + l5 * 8];
            #pragma unroll
            for (int dt = 0; dt < 2; ++dt) {
                bf16x8 av = *(const bf16x8*)&Kts[(dt * 32 + ql) * 72 + kh * 32 + kc2 * 16 + l5 * 8];
                ot[dt] = __builtin_amdgcn_mfma_f32_32x32x16_bf16(av, bp, ot[dt], 0, 0, 0);
            }
        }
    }

    // Merge the two key-halves via LDS, normalize, store.
    float lw = lac + __shfl_xor(lac, 32);     // full half-sum for this q
    float* Om = (float*)smem;                  // [128][68] fp32
    float* Lm = Om + 128 * 68;                 // [128]
    const int qi = strip * 32 + ql;

    __syncthreads();                           // all LDS reads of last iter done
    if (kh == 1) {
        #pragma unroll
        for (int dt = 0; dt < 2; ++dt)
            #pragma unroll
            for (int rr = 0; rr < 4; ++rr)
                *(f32x4*)&Om[qi * 68 + dt * 32 + 8 * rr + 4 * l5] =
                    (f32x4){ot[dt][4 * rr], ot[dt][4 * rr + 1],
                            ot[dt][4 * rr + 2], ot[dt][4 * rr + 3]};
        if (l5 == 0) Lm[qi] = lw;
    }
    __syncthreads();
    if (kh == 0) {
        const float inv = 1.0f / (lw + Lm[qi]);
        unsigned short* Ob = O + (size_t)(b * N + q0 + qi) * kDIM + h * 64;
        #pragma unroll
        for (int dt = 0; dt < 2; ++dt)
            #pragma unroll
            for (int rr = 0; rr < 4; ++rr) {
                f32x4 pv = *(const f32x4*)&Om[qi * 68 + dt * 32 + 8 * rr + 4 * l5];
                ushort4 u;
                u.x = f2bf((ot[dt][4 * rr]     + pv[0]) * inv);
                u.y = f2bf((ot[dt][4 * rr + 1] + pv[1]) * inv);
                u.z = f2bf((ot[dt][4 * rr + 2] + pv[2]) * inv);
                u.w = f2bf((ot[dt][4 * rr + 3] + pv[3]) * inv);
                *(ushort4*)(Ob + dt * 32 + 8 * rr + 4 * l5) = u;
            }
    }
}

// ---------------------------------------------------------------------------
extern "C" void kernel_launch(void* const* d_in, const int* in_sizes, int n_in,
                              void* d_out, int out_size, void* d_ws, size_t ws_size,
                              hipStream_t stream)
{
    const float* x      = (const float*)d_in[0];
    const float* ctxp   = (const float*)d_in[1];
    const float* W_q    = (const float*)d_in[2];
    const float* W_kv   = (const float*)d_in[3];
    const float* W_proj = (const float*)d_in[4];
    const float* b_proj = (const float*)d_in[5];
    float* out = (float*)d_out;

    const int B = 2, N = 2048, M = 2048;
    const int BN = B * N;        // 4096
    const int SQ = kDIM * kDIM;  // 1M

    unsigned short* p = (unsigned short*)d_ws;
    unsigned short* xb  = p; p += (size_t)BN * kDIM;   // reused as Ab
    unsigned short* cb  = p; p += (size_t)BN * kDIM;
    unsigned short* wqb = p; p += SQ;
    unsigned short* wkb = p; p += SQ;
    unsigned short* wpb = p; p += SQ;
    unsigned short* Qb  = p; p += (size_t)BN * kDIM;
    unsigned short* Kb  = p; p += (size_t)BN * kDIM;
    unsigned short* Ktb = p; p += (size_t)BN * kDIM;
    unsigned short* Ab  = xb;    // xb dead after gemm_qk

    // 1) fp32 -> bf16 for all inputs
    hipLaunchKernelGGL(cast_all, dim3(11264), dim3(256), 0, stream,
                       x, ctxp, W_q, W_kv, W_proj, xb, cb, wqb, wkb, wpb);
    // 2) z=0: Q = (0.125*log2e) * x @ Wq^T ; z=1: K(=V) = ctx @ Wkv^T (+ K^T)
    hipLaunchKernelGGL(gemm_qk, dim3(kDIM / 64, BN / 128, 2), dim3(256), 0, stream,
                       xb, cb, wqb, wkb, Qb, Kb, Ktb, 0.125f * kLog2e, M);
    // 3) A = softmax(Q K^T) V
    hipLaunchKernelGGL(attn_mfma_v5, dim3(N / 128, 16, B), dim3(512), 0, stream,
                       Qb, Kb, Ktb, Ab, N, M);
    // 4) out = A @ Wp^T + bias
    hipLaunchKernelGGL(gemm_proj, dim3(kDIM / 64, BN / 64), dim3(256), 0, stream,
                       Ab, wpb, b_proj, out);
}